// Round 4
// baseline (904.037 us; speedup 1.0000x reference)
//
#include <hip/hip_runtime.h>
#include <math.h>

// ============================================================================
// GeometricSuperpositionSearch — Cl(3,0) GA search, fp32.
// Basis order: [1, e1, e2, e3, e12, e13, e23, e123]
// Round 4: single fused k_step per depth (pred -> argmax -> dyn [-> term]),
//   one wave per row (64-thread blocks, 8 KB LDS), action in-register,
//   d=1 in-place, d=2 fuses terminal value head (no final store).
// ============================================================================

#define NOISE_MODE 0
#define DEV static __device__ __forceinline__

constexpr int Bz = 512;
constexpr int Cz = 256;
constexpr int MIDz = 128;
constexpr int Hz = 8;
constexpr int Nz = 4096;   // B*H
constexpr int Az = 5;
constexpr int NOISE_PER_D = Nz * Az;   // 20480

// ---------------- workspace layout (float offsets) ----------------
constexpr size_t OFF_ROTH  = 0;                          // 8*8
constexpr size_t OFF_ROTA  = OFF_ROTH + 64;              // 5*8
constexpr size_t OFF_ROTC  = OFF_ROTA + 40;              // 256*8
constexpr size_t OFF_EXPL  = OFF_ROTC + 2048;            // 512
constexpr size_t OFF_HV    = OFF_EXPL + 512;             // 4096
constexpr size_t OFF_FIRST = OFF_HV + 4096;              // 4096 (int)
constexpr size_t OFF_WTP   = OFF_FIRST + 4096;           // 256*128 (W'^T pred, nw folded)
constexpr size_t OFF_WTD   = OFF_WTP + (size_t)Cz * MIDz;// 256*256 (W^T dyn)
constexpr size_t OFF_A     = OFF_WTD + (size_t)Cz * Cz;  // N*C*8 state buffer

// ---------------- Cl(3,0) geometric product ----------------
DEV void gp8(const float* a, const float* b, float* c) {
  c[0] = a[0]*b[0]+a[1]*b[1]+a[2]*b[2]+a[3]*b[3]-a[4]*b[4]-a[5]*b[5]-a[6]*b[6]-a[7]*b[7];
  c[1] = a[0]*b[1]+a[1]*b[0]-a[2]*b[4]-a[3]*b[5]+a[4]*b[2]+a[5]*b[3]-a[6]*b[7]-a[7]*b[6];
  c[2] = a[0]*b[2]+a[2]*b[0]+a[1]*b[4]-a[4]*b[1]-a[3]*b[6]+a[6]*b[3]+a[5]*b[7]+a[7]*b[5];
  c[3] = a[0]*b[3]+a[3]*b[0]+a[1]*b[5]-a[5]*b[1]+a[2]*b[6]-a[6]*b[2]-a[4]*b[7]-a[7]*b[4];
  c[4] = a[0]*b[4]+a[4]*b[0]+a[1]*b[2]-a[2]*b[1]-a[5]*b[6]+a[6]*b[5]+a[3]*b[7]+a[7]*b[3];
  c[5] = a[0]*b[5]+a[5]*b[0]+a[1]*b[3]-a[3]*b[1]+a[4]*b[6]-a[6]*b[4]-a[2]*b[7]-a[7]*b[2];
  c[6] = a[0]*b[6]+a[6]*b[0]+a[2]*b[3]-a[3]*b[2]-a[4]*b[5]+a[5]*b[4]+a[1]*b[7]+a[7]*b[1];
  c[7] = a[0]*b[7]+a[7]*b[0]+a[1]*b[6]+a[6]*b[1]+a[3]*b[4]+a[4]*b[3]-a[2]*b[5]-a[5]*b[2];
}

DEV void sandwich8(const float* R, const float* x, float* y) {
  float t[8];
  gp8(R, x, t);
  float Rr[8] = {R[0], R[1], R[2], R[3], -R[4], -R[5], -R[6], -R[7]};
  gp8(t, Rr, y);
}

DEV void rotor_from_bv(const float* bv, float* R) {
  float c4 = -0.5f * bv[0], c5 = -0.5f * bv[1], c6 = -0.5f * bv[2];
  float t = sqrtf(c4*c4 + c5*c5 + c6*c6);
  float sinc = (t < 1e-6f) ? (1.0f - t*t/6.0f) : (sinf(t)/t);
  R[0] = cosf(t); R[1] = 0.f; R[2] = 0.f; R[3] = 0.f;
  R[4] = sinc*c4; R[5] = sinc*c5; R[6] = sinc*c6; R[7] = 0.f;
}

// ---------------- threefry2x32, key = (0, 42) ----------------
DEV unsigned tf_rotl(unsigned v, int n) { return (v << n) | (v >> (32 - n)); }

DEV void threefry2x32(unsigned x0, unsigned x1, unsigned& o0, unsigned& o1) {
  const unsigned k0 = 0u, k1 = 42u;
  const unsigned k2 = k0 ^ k1 ^ 0x1BD11BDAu;
  x0 += k0; x1 += k1;
#define TF_R(r) { x0 += x1; x1 = tf_rotl(x1, r); x1 ^= x0; }
  TF_R(13) TF_R(15) TF_R(26) TF_R(6)
  x0 += k1; x1 += k2 + 1u;
  TF_R(17) TF_R(29) TF_R(16) TF_R(24)
  x0 += k2; x1 += k0 + 2u;
  TF_R(13) TF_R(15) TF_R(26) TF_R(6)
  x0 += k0; x1 += k1 + 3u;
  TF_R(17) TF_R(29) TF_R(16) TF_R(24)
  x0 += k1; x1 += k2 + 4u;
  TF_R(13) TF_R(15) TF_R(26) TF_R(6)
  x0 += k2; x1 += k0 + 5u;
#undef TF_R
  o0 = x0; o1 = x1;
}

DEV float erfinv32(float x) {
  float w = -log1pf(-x * x);
  float p;
  if (w < 5.0f) {
    w = w - 2.5f;
    p = 2.81022636e-08f;
    p = fmaf(p, w, 3.43273939e-07f);
    p = fmaf(p, w, -3.5233877e-06f);
    p = fmaf(p, w, -4.39150654e-06f);
    p = fmaf(p, w, 0.00021858087f);
    p = fmaf(p, w, -0.00125372503f);
    p = fmaf(p, w, -0.00417768164f);
    p = fmaf(p, w, 0.246640727f);
    p = fmaf(p, w, 1.50140941f);
  } else {
    w = sqrtf(w) - 3.0f;
    p = -0.000200214257f;
    p = fmaf(p, w, 0.000100950558f);
    p = fmaf(p, w, 0.00134934322f);
    p = fmaf(p, w, -0.00367342844f);
    p = fmaf(p, w, 0.00573950773f);
    p = fmaf(p, w, -0.0076224613f);
    p = fmaf(p, w, 0.00943887047f);
    p = fmaf(p, w, 1.00167406f);
    p = fmaf(p, w, 2.83297682f);
  }
  return p * x;
}

DEV float noise_val(int d, int r, int a) {
  unsigned idx = (unsigned)(d * NOISE_PER_D + r * Az + a);
  unsigned o0, o1, bits;
#if NOISE_MODE == 0
  threefry2x32(0u, idx, o0, o1);
  bits = o0 ^ o1;
#elif NOISE_MODE == 1
  const unsigned HALF = (unsigned)(3 * NOISE_PER_D) / 2u;
  unsigned j = (idx < HALF) ? idx : idx - HALF;
  threefry2x32(j, j + HALF, o0, o1);
  bits = (idx < HALF) ? o0 : o1;
#elif NOISE_MODE == 2
  threefry2x32(0u, idx, o0, o1);
  bits = o1;
#else
  threefry2x32(0u, idx, o0, o1);
  bits = o0;
#endif
  const float MINV = __uint_as_float(0xBF7FFFFFu);
  float f = __uint_as_float((bits >> 9) | 0x3F800000u) - 1.0f;
  float u = fmaxf(MINV, f * 2.0f + MINV);
  const float SQRT2 = __uint_as_float(0x3FB504F3u);
  return (SQRT2 * erfinv32(u)) * 0.3f;
}

DEV float gelu_tanh(float x) {
  float x3 = (x * x) * x;
  float t = tanhf(0.7978845608028654f * (x + 0.044715f * x3));
  return x * (0.5f * (1.0f + t));
}

// pred clinear + ggelu from LDS row (x or ns), W' has nw folded; invd applied post
DEV void pred_gemm(const float4* __restrict__ xs, int l, float invd,
                   const float* __restrict__ WtP, const float* __restrict__ plb,
                   float hh[2][8]) {
  float pacc[2][8] = {{0,0,0,0,0,0,0,0},{0,0,0,0,0,0,0,0}};
#pragma unroll 4
  for (int c = 0; c < Cz; c++) {
    float4 xa = xs[c], xb = xs[Cz + c];
    float xv[8] = {xa.x, xa.y, xa.z, xa.w, xb.x, xb.y, xb.z, xb.w};
    float w0 = WtP[(size_t)c * MIDz + l];
    float w1 = WtP[(size_t)c * MIDz + 64 + l];
#pragma unroll
    for (int dd = 0; dd < 8; dd++) {
      pacc[0][dd] = fmaf(w0, xv[dd], pacc[0][dd]);
      pacc[1][dd] = fmaf(w1, xv[dd], pacc[1][dd]);
    }
  }
#pragma unroll
  for (int j = 0; j < 2; j++) {
    int o = l + 64 * j;
    float nsq = 0.f;
#pragma unroll
    for (int dd = 0; dd < 8; dd++) {
      hh[j][dd] = fmaf(pacc[j][dd], invd, plb[o * 8 + dd]);
      nsq += hh[j][dd] * hh[j][dd];
    }
    float nn = sqrtf(nsq + 1e-6f);
    float sc = gelu_tanh(nn) / (nn + 1e-6f);
#pragma unroll
    for (int dd = 0; dd < 8; dd++) hh[j][dd] *= sc;
  }
}

// ============================================================================
// kernels
// ============================================================================

__global__ void k_prep(const float* __restrict__ hyp_bv, const float* __restrict__ act_bv,
                       const float* __restrict__ rot_bv, const float* __restrict__ plw,
                       const float* __restrict__ pnw, const float* __restrict__ dlw,
                       float* __restrict__ rotH, float* __restrict__ rotA,
                       float* __restrict__ rotC, float* __restrict__ hyp_val,
                       float* __restrict__ WtP, float* __restrict__ WtD) {
  int t = blockIdx.x * 256 + threadIdx.x;   // grid 256 -> 65536 threads
  if (t < Cz * Cz)   { int c = t >> 8, o = t & 255; WtD[t] = dlw[o * Cz + c]; }
  if (t < Cz * MIDz) { int c = t >> 7, o = t & 127; WtP[t] = plw[o * Cz + c] * pnw[c]; }
  if (t < Nz) hyp_val[t] = 0.f;
  if (t < 8) rotor_from_bv(hyp_bv + t * 3, rotH + t * 8);
  else if (t < 13) rotor_from_bv(act_bv + (t - 8) * 3, rotA + (t - 8) * 8);
  else if (t >= 16 && t < 16 + Cz) rotor_from_bv(rot_bv + (t - 16) * 3, rotC + (t - 16) * 8);
}

__global__ void k_explore(const float* __restrict__ state, const float* __restrict__ w1,
                          const float* __restrict__ b1, const float* __restrict__ w2,
                          const float* __restrict__ b2, float* __restrict__ explore) {
  int b = blockIdx.x, c = threadIdx.x;
  const float4* xp = (const float4*)(state + ((size_t)b * Cz + c) * 8);
  float4 lo = xp[0], hi = xp[1];
  float g0 = lo.x * lo.x;
  float g1 = lo.y * lo.y + lo.z * lo.z + lo.w * lo.w;
  float g2 = hi.x * hi.x + hi.y * hi.y + hi.z * hi.z;
  float g3 = hi.w * hi.w;
  __shared__ float4 sm[256];
  sm[c] = make_float4(sqrtf(g0 + 1e-12f), sqrtf(g1 + 1e-12f),
                      sqrtf(g2 + 1e-12f), sqrtf(g3 + 1e-12f));
  __syncthreads();
  for (int s = 128; s > 0; s >>= 1) {
    if (c < s) {
      sm[c].x += sm[c + s].x; sm[c].y += sm[c + s].y;
      sm[c].z += sm[c + s].z; sm[c].w += sm[c + s].w;
    }
    __syncthreads();
  }
  if (c == 0) {
    float pooled[4] = {sm[0].x / 256.f, sm[0].y / 256.f, sm[0].z / 256.f, sm[0].w / 256.f};
    float theta = b2[0];
    for (int j = 0; j < 32; j++) {
      float hj = b1[j];
      for (int g = 0; g < 4; g++) hj = fmaf(pooled[g], w1[g * 32 + j], hj);
      hj = fmaxf(hj, 0.f);
      theta = fmaf(hj, w2[j], theta);
    }
    explore[b] = fabsf(tanhf(theta));
  }
}

// fused step: stage(+hyp) -> pred GEMM -> policy+noise argmax -> dyn sandwich
// -> norm/ggelu/rotor -> dyn GEMM -> residual(+store) + reward [+ terminal value]
__global__ __launch_bounds__(64, 4) void k_step(
    const float* __restrict__ src, float* __restrict__ dst, int apply_hyp,
    int dstep, int do_term,
    const float* __restrict__ rotH, const float* __restrict__ rotA,
    const float* __restrict__ rotC, const float* __restrict__ WtP,
    const float* __restrict__ plb, const float* __restrict__ pw,
    const float* __restrict__ pb, const float* __restrict__ vw,
    const float* __restrict__ vb, const float* __restrict__ dnw,
    const float* __restrict__ WtD, const float* __restrict__ dlb,
    const float* __restrict__ rw, const float* __restrict__ rb,
    const float* __restrict__ explore, float* __restrict__ hyp_val,
    int* __restrict__ first_act, float discf, float termdisc) {
  __shared__ float4 xs[2 * Cz];   // 8 KB: [c]=comps0..3, [Cz+c]=comps4..7
  int l = threadIdx.x;
  int r = blockIdx.x;
  int b = r >> 3, h = r & 7;
  const float* row = apply_hyp ? (src + (size_t)b * Cz * 8) : (src + (size_t)r * Cz * 8);
  float Rh[8];
  if (apply_hyp) {
#pragma unroll
    for (int i = 0; i < 8; i++) Rh[i] = rotH[h * 8 + i];
  }
  // ---- stage + norms ----
  float nsum = 0.f, bsum = 0.f;
#pragma unroll
  for (int g = 0; g < 4; g++) {
    int c = l + 64 * g;
    const float4* xp = (const float4*)(row + (size_t)c * 8);
    float4 v0 = xp[0], v1 = xp[1];
    float x[8] = {v0.x, v0.y, v0.z, v0.w, v1.x, v1.y, v1.z, v1.w};
    if (apply_hyp) {
      float t[8];
      sandwich8(Rh, x, t);
#pragma unroll
      for (int i = 0; i < 8; i++) x[i] = t[i];
    }
    float ss = 0.f;
#pragma unroll
    for (int i = 0; i < 8; i++) ss += x[i] * x[i];
    nsum += sqrtf(ss + 1e-6f);
    bsum += x[4] * x[4] + x[5] * x[5] + x[6] * x[6];
    xs[c]      = make_float4(x[0], x[1], x[2], x[3]);
    xs[Cz + c] = make_float4(x[4], x[5], x[6], x[7]);
  }
#pragma unroll
  for (int m = 1; m < 64; m <<= 1) {
    nsum += __shfl_xor(nsum, m);
    bsum += __shfl_xor(bsum, m);
  }
  float invd = 1.0f / (nsum / 256.f + 1e-6f);
  float bv_e = bsum / 256.f;
  __syncthreads();

  // ---- pred GEMM + policy head ----
  float hh[2][8];
  pred_gemm(xs, l, invd, WtP, plb, hh);
  float pol[Az] = {0, 0, 0, 0, 0};
#pragma unroll
  for (int j = 0; j < 2; j++) {
    int o = l + 64 * j;
#pragma unroll
    for (int k = 0; k < 3; k++) {
      float v = hh[j][1 + k];
      const float* pwj = pw + (size_t)(o * 3 + k) * Az;
#pragma unroll
      for (int a = 0; a < Az; a++) pol[a] = fmaf(v, pwj[a], pol[a]);
    }
  }
#pragma unroll
  for (int m = 1; m < 64; m <<= 1) {
#pragma unroll
    for (int a = 0; a < Az; a++) pol[a] += __shfl_xor(pol[a], m);
  }
  int best = 0;
  if (l == 0) {
    float coef = explore[b] * bv_e;
    float bs = -INFINITY;
    for (int a = 0; a < Az; a++) {
      float s = pol[a] + pb[a] + coef * noise_val(dstep, r, a);
      if (s > bs) { bs = s; best = a; }
    }
    if (dstep == 0) first_act[r] = best;
  }
  best = __shfl(best, 0);

  // ---- dyn: action sandwich (x re-read from LDS), norm ----
  float Ra[8];
#pragma unroll
  for (int i = 0; i < 8; i++) Ra[i] = rotA[best * 8 + i];
  float y[4][8];
  float nsum2 = 0.f;
#pragma unroll
  for (int g = 0; g < 4; g++) {
    int c = l + 64 * g;
    float4 xa = xs[c], xb = xs[Cz + c];
    float x[8] = {xa.x, xa.y, xa.z, xa.w, xb.x, xb.y, xb.z, xb.w};
    sandwich8(Ra, x, y[g]);
    float ss = 0.f;
#pragma unroll
    for (int i = 0; i < 8; i++) ss += y[g][i] * y[g][i];
    nsum2 += sqrtf(ss + 1e-6f);
  }
#pragma unroll
  for (int m = 1; m < 64; m <<= 1) nsum2 += __shfl_xor(nsum2, m);
  float invd2 = 1.0f / (nsum2 / 256.f + 1e-6f);
  __syncthreads();   // all pred-GEMM reads of xs done before overwrite

  // ---- ggelu + channel rotor -> h' into LDS ----
#pragma unroll
  for (int g = 0; g < 4; g++) {
    int c = l + 64 * g;
    float sc = dnw[c] * invd2;
    float hch[8];
    float nsq = 0.f;
#pragma unroll
    for (int i = 0; i < 8; i++) { hch[i] = y[g][i] * sc; nsq += hch[i] * hch[i]; }
    float nn = sqrtf(nsq + 1e-6f);
    float ge = gelu_tanh(nn) / (nn + 1e-6f);
#pragma unroll
    for (int i = 0; i < 8; i++) hch[i] *= ge;
    float Rc[8];
    const float4* rp = (const float4*)(rotC + (size_t)c * 8);
    float4 r0 = rp[0], r1 = rp[1];
    Rc[0] = r0.x; Rc[1] = r0.y; Rc[2] = r0.z; Rc[3] = r0.w;
    Rc[4] = r1.x; Rc[5] = r1.y; Rc[6] = r1.z; Rc[7] = r1.w;
    float hp[8];
    sandwich8(Rc, hch, hp);
    xs[c]      = make_float4(hp[0], hp[1], hp[2], hp[3]);
    xs[Cz + c] = make_float4(hp[4], hp[5], hp[6], hp[7]);
  }
  __syncthreads();

  // ---- dyn GEMM ----
  float acc[4][8] = {{0,0,0,0,0,0,0,0},{0,0,0,0,0,0,0,0},
                     {0,0,0,0,0,0,0,0},{0,0,0,0,0,0,0,0}};
#pragma unroll 4
  for (int c = 0; c < Cz; c++) {
    float4 xa = xs[c], xb = xs[Cz + c];
    float xv[8] = {xa.x, xa.y, xa.z, xa.w, xb.x, xb.y, xb.z, xb.w};
#pragma unroll
    for (int g = 0; g < 4; g++) {
      float wv = WtD[(size_t)c * Cz + 64 * g + l];
#pragma unroll
      for (int dd = 0; dd < 8; dd++) acc[g][dd] = fmaf(wv, xv[dd], acc[g][dd]);
    }
  }

  // ---- residual + reward (+ optional store / terminal) ----
  if (do_term) __syncthreads();   // dyn-GEMM xs reads done before term overwrite
  float rsum = 0.f, tsum = 0.f;
  float* drow = dst + (size_t)r * Cz * 8;
#pragma unroll
  for (int g = 0; g < 4; g++) {
    int o = l + 64 * g;
    float out[8];
    float ss = 0.f;
#pragma unroll
    for (int dd = 0; dd < 8; dd++) {
      out[dd] = y[g][dd] + (acc[g][dd] + dlb[o * 8 + dd]);
      ss += out[dd] * out[dd];
    }
    rsum = fmaf(out[0], rw[o], rsum);
    if (do_term) {
      tsum += sqrtf(ss + 1e-6f);
      xs[o]      = make_float4(out[0], out[1], out[2], out[3]);
      xs[Cz + o] = make_float4(out[4], out[5], out[6], out[7]);
    } else {
      float4* op = (float4*)(drow + (size_t)o * 8);
      op[0] = make_float4(out[0], out[1], out[2], out[3]);
      op[1] = make_float4(out[4], out[5], out[6], out[7]);
    }
  }
#pragma unroll
  for (int m = 1; m < 64; m <<= 1) rsum += __shfl_xor(rsum, m);
  float hv_add = discf * (rsum + rb[0]);

  if (do_term) {
#pragma unroll
    for (int m = 1; m < 64; m <<= 1) tsum += __shfl_xor(tsum, m);
    float invd3 = 1.0f / (tsum / 256.f + 1e-6f);
    __syncthreads();
    float th[2][8];
    pred_gemm(xs, l, invd3, WtP, plb, th);
    float v = fmaf(th[0][0], vw[l], th[1][0] * vw[l + 64]);
#pragma unroll
    for (int m = 1; m < 64; m <<= 1) v += __shfl_xor(v, m);
    hv_add += termdisc * (v + vb[0]);
  }
  if (l == 0) hyp_val[r] += hv_add;
}

__global__ void k_out(const float* __restrict__ hyp_val, const int* __restrict__ first_act,
                      float* __restrict__ out) {
  int b = blockIdx.x * blockDim.x + threadIdx.x;
  if (b >= Bz) return;
  float hv[Hz];
  float m = -INFINITY;
#pragma unroll
  for (int h = 0; h < Hz; h++) { hv[h] = hyp_val[b * Hz + h]; m = fmaxf(m, hv[h]); }
  float e[Hz];
  float se = 0.f;
#pragma unroll
  for (int h = 0; h < Hz; h++) { e[h] = expf(hv[h] - m); se += e[h]; }
  float ap[Az] = {0, 0, 0, 0, 0};
#pragma unroll
  for (int h = 0; h < Hz; h++) ap[first_act[b * Hz + h]] += e[h] / se;
  float tot = 0.f;
#pragma unroll
  for (int a = 0; a < Az; a++) tot += ap[a];
  float dn = fmaxf(tot, 1e-8f);
#pragma unroll
  for (int a = 0; a < Az; a++) out[b * Az + a] = ap[a] / dn;
}

// ============================================================================

extern "C" void kernel_launch(void* const* d_in, const int* in_sizes, int n_in,
                              void* d_out, int out_size, void* d_ws, size_t ws_size,
                              hipStream_t stream) {
  const float* state      = (const float*)d_in[0];
  const float* hyp_bv     = (const float*)d_in[1];
  const float* sp_w1      = (const float*)d_in[2];
  const float* sp_b1      = (const float*)d_in[3];
  const float* sp_w2      = (const float*)d_in[4];
  const float* sp_b2      = (const float*)d_in[5];
  const float* p_norm_w   = (const float*)d_in[6];
  const float* p_lin_w    = (const float*)d_in[7];
  const float* p_lin_b    = (const float*)d_in[8];
  const float* p_vw       = (const float*)d_in[9];
  const float* p_vb       = (const float*)d_in[10];
  const float* p_pw       = (const float*)d_in[11];
  const float* p_pb       = (const float*)d_in[12];
  const float* act_bv     = (const float*)d_in[13];
  const float* d_norm_w   = (const float*)d_in[14];
  const float* d_rotor_bv = (const float*)d_in[15];
  const float* d_lin_w    = (const float*)d_in[16];
  const float* d_lin_b    = (const float*)d_in[17];
  const float* d_rw       = (const float*)d_in[18];
  const float* d_rb       = (const float*)d_in[19];
  float* out = (float*)d_out;
  float* ws  = (float*)d_ws;

  float* rotH    = ws + OFF_ROTH;
  float* rotA    = ws + OFF_ROTA;
  float* rotC    = ws + OFF_ROTC;
  float* explore = ws + OFF_EXPL;
  float* hyp_val = ws + OFF_HV;
  int*   first   = (int*)(ws + OFF_FIRST);
  float* WtP     = ws + OFF_WTP;
  float* WtD     = ws + OFF_WTD;
  float* bufA    = ws + OFF_A;

  k_prep<<<256, 256, 0, stream>>>(hyp_bv, act_bv, d_rotor_bv, p_lin_w, p_norm_w,
                                  d_lin_w, rotH, rotA, rotC, hyp_val, WtP, WtD);
  k_explore<<<Bz, 256, 0, stream>>>(state, sp_w1, sp_b1, sp_w2, sp_b2, explore);

  const float d1 = 0.99f, d2 = 0.99f * 0.99f, d3 = 0.99f * 0.99f * 0.99f;
  // d=0: state(+hyp) -> bufA
  k_step<<<Nz, 64, 0, stream>>>(state, bufA, 1, 0, 0, rotH, rotA, rotC, WtP, p_lin_b,
                                p_pw, p_pb, p_vw, p_vb, d_norm_w, WtD, d_lin_b,
                                d_rw, d_rb, explore, hyp_val, first, 1.0f, 0.f);
  // d=1: bufA in-place
  k_step<<<Nz, 64, 0, stream>>>(bufA, bufA, 0, 1, 0, rotH, rotA, rotC, WtP, p_lin_b,
                                p_pw, p_pb, p_vw, p_vb, d_norm_w, WtD, d_lin_b,
                                d_rw, d_rb, explore, hyp_val, first, d1, 0.f);
  // d=2: bufA -> (no store) + terminal value
  k_step<<<Nz, 64, 0, stream>>>(bufA, bufA, 0, 2, 1, rotH, rotA, rotC, WtP, p_lin_b,
                                p_pw, p_pb, p_vw, p_vb, d_norm_w, WtD, d_lin_b,
                                d_rw, d_rb, explore, hyp_val, first, d2, d3);
  k_out<<<2, 256, 0, stream>>>(hyp_val, first, out);
}

// Round 5
// 379.059 us; speedup vs baseline: 2.3849x; 2.3849x over previous
//
#include <hip/hip_runtime.h>
#include <math.h>

// ============================================================================
// GeometricSuperpositionSearch — Cl(3,0) GA search, fp32.
// Basis order: [1, e1, e2, e3, e12, e13, e23, e123]
// Round 5: fused per-depth k_step, 256 threads / 4 rows per block (restores
//   4-wave lockstep L1 sharing of weight streams lost in r4), lane<->channel
//   remap (lane l owns channels 4l..4l+3) so dyn residual folds into acc init,
//   float4/float2 weight loads, parallel (lane<5) noise argmax.
// ============================================================================

#define NOISE_MODE 0
#define DEV static __device__ __forceinline__

constexpr int Bz = 512;
constexpr int Cz = 256;
constexpr int MIDz = 128;
constexpr int Hz = 8;
constexpr int Nz = 4096;   // B*H
constexpr int Az = 5;
constexpr int NOISE_PER_D = Nz * Az;   // 20480

// ---------------- workspace layout (float offsets) ----------------
constexpr size_t OFF_ROTH  = 0;                          // 8*8
constexpr size_t OFF_ROTA  = OFF_ROTH + 64;              // 5*8
constexpr size_t OFF_ROTC  = OFF_ROTA + 40;              // 256*8
constexpr size_t OFF_EXPL  = OFF_ROTC + 2048;            // 512
constexpr size_t OFF_HV    = OFF_EXPL + 512;             // 4096
constexpr size_t OFF_FIRST = OFF_HV + 4096;              // 4096 (int)
constexpr size_t OFF_WTP   = OFF_FIRST + 4096;           // [c][o] 256*128, nw folded
constexpr size_t OFF_WTD   = OFF_WTP + (size_t)Cz * MIDz;// [c][o] 256*256
constexpr size_t OFF_A     = OFF_WTD + (size_t)Cz * Cz;  // N*C*8 state buffer

// ---------------- Cl(3,0) geometric product ----------------
DEV void gp8(const float* a, const float* b, float* c) {
  c[0] = a[0]*b[0]+a[1]*b[1]+a[2]*b[2]+a[3]*b[3]-a[4]*b[4]-a[5]*b[5]-a[6]*b[6]-a[7]*b[7];
  c[1] = a[0]*b[1]+a[1]*b[0]-a[2]*b[4]-a[3]*b[5]+a[4]*b[2]+a[5]*b[3]-a[6]*b[7]-a[7]*b[6];
  c[2] = a[0]*b[2]+a[2]*b[0]+a[1]*b[4]-a[4]*b[1]-a[3]*b[6]+a[6]*b[3]+a[5]*b[7]+a[7]*b[5];
  c[3] = a[0]*b[3]+a[3]*b[0]+a[1]*b[5]-a[5]*b[1]+a[2]*b[6]-a[6]*b[2]-a[4]*b[7]-a[7]*b[4];
  c[4] = a[0]*b[4]+a[4]*b[0]+a[1]*b[2]-a[2]*b[1]-a[5]*b[6]+a[6]*b[5]+a[3]*b[7]+a[7]*b[3];
  c[5] = a[0]*b[5]+a[5]*b[0]+a[1]*b[3]-a[3]*b[1]+a[4]*b[6]-a[6]*b[4]-a[2]*b[7]-a[7]*b[2];
  c[6] = a[0]*b[6]+a[6]*b[0]+a[2]*b[3]-a[3]*b[2]-a[4]*b[5]+a[5]*b[4]+a[1]*b[7]+a[7]*b[1];
  c[7] = a[0]*b[7]+a[7]*b[0]+a[1]*b[6]+a[6]*b[1]+a[3]*b[4]+a[4]*b[3]-a[2]*b[5]-a[5]*b[2];
}

DEV void sandwich8(const float* R, const float* x, float* y) {
  float t[8];
  gp8(R, x, t);
  float Rr[8] = {R[0], R[1], R[2], R[3], -R[4], -R[5], -R[6], -R[7]};
  gp8(t, Rr, y);
}

DEV void rotor_from_bv(const float* bv, float* R) {
  float c4 = -0.5f * bv[0], c5 = -0.5f * bv[1], c6 = -0.5f * bv[2];
  float t = sqrtf(c4*c4 + c5*c5 + c6*c6);
  float sinc = (t < 1e-6f) ? (1.0f - t*t/6.0f) : (sinf(t)/t);
  R[0] = cosf(t); R[1] = 0.f; R[2] = 0.f; R[3] = 0.f;
  R[4] = sinc*c4; R[5] = sinc*c5; R[6] = sinc*c6; R[7] = 0.f;
}

// ---------------- threefry2x32, key = (0, 42) ----------------
DEV unsigned tf_rotl(unsigned v, int n) { return (v << n) | (v >> (32 - n)); }

DEV void threefry2x32(unsigned x0, unsigned x1, unsigned& o0, unsigned& o1) {
  const unsigned k0 = 0u, k1 = 42u;
  const unsigned k2 = k0 ^ k1 ^ 0x1BD11BDAu;
  x0 += k0; x1 += k1;
#define TF_R(r) { x0 += x1; x1 = tf_rotl(x1, r); x1 ^= x0; }
  TF_R(13) TF_R(15) TF_R(26) TF_R(6)
  x0 += k1; x1 += k2 + 1u;
  TF_R(17) TF_R(29) TF_R(16) TF_R(24)
  x0 += k2; x1 += k0 + 2u;
  TF_R(13) TF_R(15) TF_R(26) TF_R(6)
  x0 += k0; x1 += k1 + 3u;
  TF_R(17) TF_R(29) TF_R(16) TF_R(24)
  x0 += k1; x1 += k2 + 4u;
  TF_R(13) TF_R(15) TF_R(26) TF_R(6)
  x0 += k2; x1 += k0 + 5u;
#undef TF_R
  o0 = x0; o1 = x1;
}

DEV float erfinv32(float x) {
  float w = -log1pf(-x * x);
  float p;
  if (w < 5.0f) {
    w = w - 2.5f;
    p = 2.81022636e-08f;
    p = fmaf(p, w, 3.43273939e-07f);
    p = fmaf(p, w, -3.5233877e-06f);
    p = fmaf(p, w, -4.39150654e-06f);
    p = fmaf(p, w, 0.00021858087f);
    p = fmaf(p, w, -0.00125372503f);
    p = fmaf(p, w, -0.00417768164f);
    p = fmaf(p, w, 0.246640727f);
    p = fmaf(p, w, 1.50140941f);
  } else {
    w = sqrtf(w) - 3.0f;
    p = -0.000200214257f;
    p = fmaf(p, w, 0.000100950558f);
    p = fmaf(p, w, 0.00134934322f);
    p = fmaf(p, w, -0.00367342844f);
    p = fmaf(p, w, 0.00573950773f);
    p = fmaf(p, w, -0.0076224613f);
    p = fmaf(p, w, 0.00943887047f);
    p = fmaf(p, w, 1.00167406f);
    p = fmaf(p, w, 2.83297682f);
  }
  return p * x;
}

DEV float noise_val(int d, int r, int a) {
  unsigned idx = (unsigned)(d * NOISE_PER_D + r * Az + a);
  unsigned o0, o1, bits;
#if NOISE_MODE == 0
  threefry2x32(0u, idx, o0, o1);
  bits = o0 ^ o1;
#elif NOISE_MODE == 1
  const unsigned HALF = (unsigned)(3 * NOISE_PER_D) / 2u;
  unsigned j = (idx < HALF) ? idx : idx - HALF;
  threefry2x32(j, j + HALF, o0, o1);
  bits = (idx < HALF) ? o0 : o1;
#elif NOISE_MODE == 2
  threefry2x32(0u, idx, o0, o1);
  bits = o1;
#else
  threefry2x32(0u, idx, o0, o1);
  bits = o0;
#endif
  const float MINV = __uint_as_float(0xBF7FFFFFu);
  float f = __uint_as_float((bits >> 9) | 0x3F800000u) - 1.0f;
  float u = fmaxf(MINV, f * 2.0f + MINV);
  const float SQRT2 = __uint_as_float(0x3FB504F3u);
  return (SQRT2 * erfinv32(u)) * 0.3f;
}

DEV float gelu_tanh(float x) {
  float x3 = (x * x) * x;
  float t = tanhf(0.7978845608028654f * (x + 0.044715f * x3));
  return x * (0.5f * (1.0f + t));
}

// pred clinear + ggelu from LDS row; lane l -> outputs o=2l, 2l+1
DEV void pred_gemm(const float4* __restrict__ X, int l, float invd,
                   const float* __restrict__ WtP, const float* __restrict__ plb,
                   float hh[2][8]) {
  float pacc[2][8] = {{0,0,0,0,0,0,0,0},{0,0,0,0,0,0,0,0}};
  const float2* Wp2 = (const float2*)WtP;
#pragma unroll 4
  for (int c = 0; c < Cz; c++) {
    float4 xa = X[c], xb = X[Cz + c];
    float xv[8] = {xa.x, xa.y, xa.z, xa.w, xb.x, xb.y, xb.z, xb.w};
    float2 wv = Wp2[(size_t)c * 64 + l];
#pragma unroll
    for (int dd = 0; dd < 8; dd++) {
      pacc[0][dd] = fmaf(wv.x, xv[dd], pacc[0][dd]);
      pacc[1][dd] = fmaf(wv.y, xv[dd], pacc[1][dd]);
    }
  }
#pragma unroll
  for (int j = 0; j < 2; j++) {
    int o = 2 * l + j;
    float nsq = 0.f;
#pragma unroll
    for (int dd = 0; dd < 8; dd++) {
      hh[j][dd] = fmaf(pacc[j][dd], invd, plb[o * 8 + dd]);
      nsq += hh[j][dd] * hh[j][dd];
    }
    float nn = sqrtf(nsq + 1e-6f);
    float sc = gelu_tanh(nn) / (nn + 1e-6f);
#pragma unroll
    for (int dd = 0; dd < 8; dd++) hh[j][dd] *= sc;
  }
}

// ============================================================================
// kernels
// ============================================================================

__global__ void k_prep(const float* __restrict__ hyp_bv, const float* __restrict__ act_bv,
                       const float* __restrict__ rot_bv, const float* __restrict__ plw,
                       const float* __restrict__ pnw, const float* __restrict__ dlw,
                       float* __restrict__ rotH, float* __restrict__ rotA,
                       float* __restrict__ rotC, float* __restrict__ hyp_val,
                       float* __restrict__ WtP, float* __restrict__ WtD) {
  int t = blockIdx.x * 256 + threadIdx.x;   // grid 256 -> 65536 threads
  if (t < Cz * Cz)   { int c = t >> 8, o = t & 255; WtD[t] = dlw[o * Cz + c]; }
  if (t < Cz * MIDz) { int c = t >> 7, o = t & 127; WtP[t] = plw[o * Cz + c] * pnw[c]; }
  if (t < Nz) hyp_val[t] = 0.f;
  if (t < 8) rotor_from_bv(hyp_bv + t * 3, rotH + t * 8);
  else if (t < 13) rotor_from_bv(act_bv + (t - 8) * 3, rotA + (t - 8) * 8);
  else if (t >= 16 && t < 16 + Cz) rotor_from_bv(rot_bv + (t - 16) * 3, rotC + (t - 16) * 8);
}

__global__ void k_explore(const float* __restrict__ state, const float* __restrict__ w1,
                          const float* __restrict__ b1, const float* __restrict__ w2,
                          const float* __restrict__ b2, float* __restrict__ explore) {
  int b = blockIdx.x, c = threadIdx.x;
  const float4* xp = (const float4*)(state + ((size_t)b * Cz + c) * 8);
  float4 lo = xp[0], hi = xp[1];
  float g0 = lo.x * lo.x;
  float g1 = lo.y * lo.y + lo.z * lo.z + lo.w * lo.w;
  float g2 = hi.x * hi.x + hi.y * hi.y + hi.z * hi.z;
  float g3 = hi.w * hi.w;
  __shared__ float4 sm[256];
  sm[c] = make_float4(sqrtf(g0 + 1e-12f), sqrtf(g1 + 1e-12f),
                      sqrtf(g2 + 1e-12f), sqrtf(g3 + 1e-12f));
  __syncthreads();
  for (int s = 128; s > 0; s >>= 1) {
    if (c < s) {
      sm[c].x += sm[c + s].x; sm[c].y += sm[c + s].y;
      sm[c].z += sm[c + s].z; sm[c].w += sm[c + s].w;
    }
    __syncthreads();
  }
  if (c == 0) {
    float pooled[4] = {sm[0].x / 256.f, sm[0].y / 256.f, sm[0].z / 256.f, sm[0].w / 256.f};
    float theta = b2[0];
    for (int j = 0; j < 32; j++) {
      float hj = b1[j];
      for (int g = 0; g < 4; g++) hj = fmaf(pooled[g], w1[g * 32 + j], hj);
      hj = fmaxf(hj, 0.f);
      theta = fmaf(hj, w2[j], theta);
    }
    explore[b] = fabsf(tanhf(theta));
  }
}

// fused step: 4 rows/block, wave w = row blockIdx*4+w, lane l owns ch 4l..4l+3
__global__ __launch_bounds__(256, 4) void k_step(
    const float* __restrict__ src, float* __restrict__ dst, int apply_hyp,
    int dstep, int do_term,
    const float* __restrict__ rotH, const float* __restrict__ rotA,
    const float* __restrict__ rotC, const float* __restrict__ WtP,
    const float* __restrict__ plb, const float* __restrict__ pw,
    const float* __restrict__ pb, const float* __restrict__ vw,
    const float* __restrict__ vb, const float* __restrict__ dnw,
    const float* __restrict__ WtD, const float* __restrict__ dlb,
    const float* __restrict__ rw, const float* __restrict__ rb,
    const float* __restrict__ explore, float* __restrict__ hyp_val,
    int* __restrict__ first_act, float discf, float termdisc) {
  __shared__ float4 xs[4][2 * Cz];   // 32 KB, wave-private 8 KB slices
  int w = threadIdx.x >> 6, l = threadIdx.x & 63;
  int r = blockIdx.x * 4 + w;
  int b = r >> 3, h = r & 7;
  float4* X = xs[w];
  const float* row = apply_hyp ? (src + (size_t)b * Cz * 8) : (src + (size_t)r * Cz * 8);
  float Rh[8];
  if (apply_hyp) {
#pragma unroll
    for (int i = 0; i < 8; i++) Rh[i] = rotH[h * 8 + i];
  }
  // ---- stage + norms: lane l handles c = 4l..4l+3 ----
  float nsum = 0.f, bsum = 0.f;
#pragma unroll
  for (int k = 0; k < 4; k++) {
    int c = 4 * l + k;
    const float4* xp = (const float4*)(row + (size_t)c * 8);
    float4 v0 = xp[0], v1 = xp[1];
    float x[8] = {v0.x, v0.y, v0.z, v0.w, v1.x, v1.y, v1.z, v1.w};
    if (apply_hyp) {
      float t[8];
      sandwich8(Rh, x, t);
#pragma unroll
      for (int i = 0; i < 8; i++) x[i] = t[i];
    }
    float ss = 0.f;
#pragma unroll
    for (int i = 0; i < 8; i++) ss += x[i] * x[i];
    nsum += sqrtf(ss + 1e-6f);
    bsum += x[4] * x[4] + x[5] * x[5] + x[6] * x[6];
    X[c]      = make_float4(x[0], x[1], x[2], x[3]);
    X[Cz + c] = make_float4(x[4], x[5], x[6], x[7]);
  }
#pragma unroll
  for (int m = 1; m < 64; m <<= 1) {
    nsum += __shfl_xor(nsum, m);
    bsum += __shfl_xor(bsum, m);
  }
  float invd = 1.0f / (nsum / 256.f + 1e-6f);
  float bv_e = bsum / 256.f;
  __syncthreads();

  // ---- pred GEMM + policy head ----
  float hh[2][8];
  pred_gemm(X, l, invd, WtP, plb, hh);
  float pol[Az] = {0, 0, 0, 0, 0};
#pragma unroll
  for (int j = 0; j < 2; j++) {
    int o = 2 * l + j;
#pragma unroll
    for (int k = 0; k < 3; k++) {
      float v = hh[j][1 + k];
      const float* pwj = pw + (size_t)(o * 3 + k) * Az;
#pragma unroll
      for (int a = 0; a < Az; a++) pol[a] = fmaf(v, pwj[a], pol[a]);
    }
  }
#pragma unroll
  for (int m = 1; m < 64; m <<= 1) {
#pragma unroll
    for (int a = 0; a < Az; a++) pol[a] += __shfl_xor(pol[a], m);
  }
  // parallel noise: lanes 0..4 each compute one candidate score
  float coef = explore[b] * bv_e;
  float sa = -INFINITY;
  if (l < Az) sa = (pol[l] + pb[l]) + coef * noise_val(dstep, r, l);
  int best = 0;
  float bs = -INFINITY;
#pragma unroll
  for (int a = 0; a < Az; a++) {
    float s = __shfl(sa, a);
    if (s > bs) { bs = s; best = a; }
  }
  if (dstep == 0 && l == 0) first_act[r] = best;

  // ---- dyn: action sandwich from LDS ----
  float Ra[8];
#pragma unroll
  for (int i = 0; i < 8; i++) Ra[i] = rotA[best * 8 + i];
  float y[4][8];
  float nsum2 = 0.f;
#pragma unroll
  for (int k = 0; k < 4; k++) {
    int c = 4 * l + k;
    float4 xa = X[c], xb = X[Cz + c];
    float x[8] = {xa.x, xa.y, xa.z, xa.w, xb.x, xb.y, xb.z, xb.w};
    sandwich8(Ra, x, y[k]);
    float ss = 0.f;
#pragma unroll
    for (int i = 0; i < 8; i++) ss += y[k][i] * y[k][i];
    nsum2 += sqrtf(ss + 1e-6f);
  }
#pragma unroll
  for (int m = 1; m < 64; m <<= 1) nsum2 += __shfl_xor(nsum2, m);
  float invd2 = 1.0f / (nsum2 / 256.f + 1e-6f);

  // ---- ggelu + channel rotor -> h' into X ----
#pragma unroll
  for (int k = 0; k < 4; k++) {
    int c = 4 * l + k;
    float sc = dnw[c] * invd2;
    float hch[8];
    float nsq = 0.f;
#pragma unroll
    for (int i = 0; i < 8; i++) { hch[i] = y[k][i] * sc; nsq += hch[i] * hch[i]; }
    float nn = sqrtf(nsq + 1e-6f);
    float ge = gelu_tanh(nn) / (nn + 1e-6f);
#pragma unroll
    for (int i = 0; i < 8; i++) hch[i] *= ge;
    float Rc[8];
    const float4* rp = (const float4*)(rotC + (size_t)c * 8);
    float4 r0 = rp[0], r1 = rp[1];
    Rc[0] = r0.x; Rc[1] = r0.y; Rc[2] = r0.z; Rc[3] = r0.w;
    Rc[4] = r1.x; Rc[5] = r1.y; Rc[6] = r1.z; Rc[7] = r1.w;
    float hp[8];
    sandwich8(Rc, hch, hp);
    X[c]      = make_float4(hp[0], hp[1], hp[2], hp[3]);
    X[Cz + c] = make_float4(hp[4], hp[5], hp[6], hp[7]);
  }
  __syncthreads();

  // ---- dyn GEMM: o = 4l+g; acc init = residual y + bias ----
  float acc[4][8];
#pragma unroll
  for (int g = 0; g < 4; g++) {
    int o = 4 * l + g;
#pragma unroll
    for (int dd = 0; dd < 8; dd++) acc[g][dd] = y[g][dd] + dlb[o * 8 + dd];
  }
  const float4* Wd4 = (const float4*)WtD;
#pragma unroll 4
  for (int c = 0; c < Cz; c++) {
    float4 xa = X[c], xb = X[Cz + c];
    float xv[8] = {xa.x, xa.y, xa.z, xa.w, xb.x, xb.y, xb.z, xb.w};
    float4 w4 = Wd4[(size_t)c * 64 + l];
#pragma unroll
    for (int dd = 0; dd < 8; dd++) {
      acc[0][dd] = fmaf(w4.x, xv[dd], acc[0][dd]);
      acc[1][dd] = fmaf(w4.y, xv[dd], acc[1][dd]);
      acc[2][dd] = fmaf(w4.z, xv[dd], acc[2][dd]);
      acc[3][dd] = fmaf(w4.w, xv[dd], acc[3][dd]);
    }
  }

  // ---- reward + store / terminal ----
  float rsum = 0.f;
  float hv_add;
  if (!do_term) {
    float* drow = dst + (size_t)r * Cz * 8;
#pragma unroll
    for (int g = 0; g < 4; g++) {
      int o = 4 * l + g;
      rsum = fmaf(acc[g][0], rw[o], rsum);
      float4* op = (float4*)(drow + (size_t)o * 8);
      op[0] = make_float4(acc[g][0], acc[g][1], acc[g][2], acc[g][3]);
      op[1] = make_float4(acc[g][4], acc[g][5], acc[g][6], acc[g][7]);
    }
#pragma unroll
    for (int m = 1; m < 64; m <<= 1) rsum += __shfl_xor(rsum, m);
    hv_add = discf * (rsum + rb[0]);
  } else {
    __syncthreads();   // all dyn-GEMM reads of X done before overwrite
    float tsum = 0.f;
#pragma unroll
    for (int g = 0; g < 4; g++) {
      int o = 4 * l + g;
      rsum = fmaf(acc[g][0], rw[o], rsum);
      float ss = 0.f;
#pragma unroll
      for (int dd = 0; dd < 8; dd++) ss += acc[g][dd] * acc[g][dd];
      tsum += sqrtf(ss + 1e-6f);
      X[o]      = make_float4(acc[g][0], acc[g][1], acc[g][2], acc[g][3]);
      X[Cz + o] = make_float4(acc[g][4], acc[g][5], acc[g][6], acc[g][7]);
    }
#pragma unroll
    for (int m = 1; m < 64; m <<= 1) {
      rsum += __shfl_xor(rsum, m);
      tsum += __shfl_xor(tsum, m);
    }
    float invd3 = 1.0f / (tsum / 256.f + 1e-6f);
    __syncthreads();
    float th[2][8];
    pred_gemm(X, l, invd3, WtP, plb, th);
    float v = fmaf(th[0][0], vw[2 * l], th[1][0] * vw[2 * l + 1]);
#pragma unroll
    for (int m = 1; m < 64; m <<= 1) v += __shfl_xor(v, m);
    hv_add = discf * (rsum + rb[0]) + termdisc * (v + vb[0]);
  }
  if (l == 0) hyp_val[r] += hv_add;
}

__global__ void k_out(const float* __restrict__ hyp_val, const int* __restrict__ first_act,
                      float* __restrict__ out) {
  int b = blockIdx.x * blockDim.x + threadIdx.x;
  if (b >= Bz) return;
  float hv[Hz];
  float m = -INFINITY;
#pragma unroll
  for (int h = 0; h < Hz; h++) { hv[h] = hyp_val[b * Hz + h]; m = fmaxf(m, hv[h]); }
  float e[Hz];
  float se = 0.f;
#pragma unroll
  for (int h = 0; h < Hz; h++) { e[h] = expf(hv[h] - m); se += e[h]; }
  float ap[Az] = {0, 0, 0, 0, 0};
#pragma unroll
  for (int h = 0; h < Hz; h++) ap[first_act[b * Hz + h]] += e[h] / se;
  float tot = 0.f;
#pragma unroll
  for (int a = 0; a < Az; a++) tot += ap[a];
  float dn = fmaxf(tot, 1e-8f);
#pragma unroll
  for (int a = 0; a < Az; a++) out[b * Az + a] = ap[a] / dn;
}

// ============================================================================

extern "C" void kernel_launch(void* const* d_in, const int* in_sizes, int n_in,
                              void* d_out, int out_size, void* d_ws, size_t ws_size,
                              hipStream_t stream) {
  const float* state      = (const float*)d_in[0];
  const float* hyp_bv     = (const float*)d_in[1];
  const float* sp_w1      = (const float*)d_in[2];
  const float* sp_b1      = (const float*)d_in[3];
  const float* sp_w2      = (const float*)d_in[4];
  const float* sp_b2      = (const float*)d_in[5];
  const float* p_norm_w   = (const float*)d_in[6];
  const float* p_lin_w    = (const float*)d_in[7];
  const float* p_lin_b    = (const float*)d_in[8];
  const float* p_vw       = (const float*)d_in[9];
  const float* p_vb       = (const float*)d_in[10];
  const float* p_pw       = (const float*)d_in[11];
  const float* p_pb       = (const float*)d_in[12];
  const float* act_bv     = (const float*)d_in[13];
  const float* d_norm_w   = (const float*)d_in[14];
  const float* d_rotor_bv = (const float*)d_in[15];
  const float* d_lin_w    = (const float*)d_in[16];
  const float* d_lin_b    = (const float*)d_in[17];
  const float* d_rw       = (const float*)d_in[18];
  const float* d_rb       = (const float*)d_in[19];
  float* out = (float*)d_out;
  float* ws  = (float*)d_ws;

  float* rotH    = ws + OFF_ROTH;
  float* rotA    = ws + OFF_ROTA;
  float* rotC    = ws + OFF_ROTC;
  float* explore = ws + OFF_EXPL;
  float* hyp_val = ws + OFF_HV;
  int*   first   = (int*)(ws + OFF_FIRST);
  float* WtP     = ws + OFF_WTP;
  float* WtD     = ws + OFF_WTD;
  float* bufA    = ws + OFF_A;

  k_prep<<<256, 256, 0, stream>>>(hyp_bv, act_bv, d_rotor_bv, p_lin_w, p_norm_w,
                                  d_lin_w, rotH, rotA, rotC, hyp_val, WtP, WtD);
  k_explore<<<Bz, 256, 0, stream>>>(state, sp_w1, sp_b1, sp_w2, sp_b2, explore);

  const float d1 = 0.99f, d2 = 0.99f * 0.99f, d3 = 0.99f * 0.99f * 0.99f;
  // d=0: state(+hyp) -> bufA
  k_step<<<Nz / 4, 256, 0, stream>>>(state, bufA, 1, 0, 0, rotH, rotA, rotC, WtP,
                                     p_lin_b, p_pw, p_pb, p_vw, p_vb, d_norm_w, WtD,
                                     d_lin_b, d_rw, d_rb, explore, hyp_val, first,
                                     1.0f, 0.f);
  // d=1: bufA in-place
  k_step<<<Nz / 4, 256, 0, stream>>>(bufA, bufA, 0, 1, 0, rotH, rotA, rotC, WtP,
                                     p_lin_b, p_pw, p_pb, p_vw, p_vb, d_norm_w, WtD,
                                     d_lin_b, d_rw, d_rb, explore, hyp_val, first,
                                     d1, 0.f);
  // d=2: no store + fused terminal value
  k_step<<<Nz / 4, 256, 0, stream>>>(bufA, bufA, 0, 2, 1, rotH, rotA, rotC, WtP,
                                     p_lin_b, p_pw, p_pb, p_vw, p_vb, d_norm_w, WtD,
                                     d_lin_b, d_rw, d_rb, explore, hyp_val, first,
                                     d2, d3);
  k_out<<<2, 256, 0, stream>>>(hyp_val, first, out);
}